// Round 9
// baseline (485.662 us; speedup 1.0000x reference)
//
#include <hip/hip_runtime.h>
#include <cstddef>

#define T_SEQ 11
#define STEPS 80

typedef _Float16 f16;
typedef _Float16 f16x4 __attribute__((ext_vector_type(4)));
typedef _Float16 f16x8 __attribute__((ext_vector_type(8)));
typedef float    f32x4 __attribute__((ext_vector_type(4)));
typedef float    f32x16 __attribute__((ext_vector_type(16)));

// Gate prescale folded into weights/biases: sigmoid args x -log2(e), tanh
// (n-path) args x +2*log2(e) -> epilogue uses raw exp2/rcp.
#define SRC (-1.44269504f)
#define SNC ( 2.88539008f)

__device__ __forceinline__ f32x16 mfma32(f16x8 a, f16x8 b, f32x16 c) {
    return __builtin_amdgcn_mfma_f32_32x32x16_f16(a, b, c, 0, 0, 0);
}
__device__ __forceinline__ float exp2r(float x) { return __builtin_amdgcn_exp2f(x); }

// ---- 32x32x16 fragment maps (HW-verified family) ----
// A: lane(b31,hi) holds A[rowBase+b31][f*16 + hi*8 + i], i=0..7
// B: lane(b31,hi) holds B[f*16 + hi*8 + i][b31]
// C/D: col = lane&31, row = (r&3) + 8*(r>>2) + 4*hi, r=0..15
__device__ __forceinline__ f16x8 afrag32(const float* __restrict__ W, int rowBase,
                                         int b31, int hi, int f, float sc) {
    f16x8 r;
    const int row = rowBase + b31, k0 = f * 16 + hi * 8;
    #pragma unroll
    for (int i = 0; i < 8; ++i) r[i] = (f16)(sc * W[row * 64 + k0 + i]);
    return r;
}
// Composed decoder-l0 gi weights: sc*(Wih0[row][0]*fcW[0][k] + Wih0[row][1]*fcW[1][k])
__device__ __forceinline__ f16x8 cfrag32(const float* __restrict__ Wih0,
                                         const float* __restrict__ fcW, int rowBase,
                                         int b31, int hi, int f, float sc) {
    f16x8 r;
    const int row = rowBase + b31, k0 = f * 16 + hi * 8;
    #pragma unroll
    for (int i = 0; i < 8; ++i)
        r[i] = (f16)(sc * (Wih0[row * 2] * fcW[k0 + i] + Wih0[row * 2 + 1] * fcW[64 + k0 + i]));
    return r;
}
// extras A-frag: K=16 side-channel carrying x-weights (k0,k1) and bias as
// double-f16 (k6 = b_hi, k7 = 256*b_lo, paired with B = [x0,x1,0,0,0,0,1,1/256]).
__device__ __forceinline__ f16x8 ex_make(float w0, float w1, float b, int hi) {
    f16x8 r;
    #pragma unroll
    for (int i = 0; i < 8; ++i) r[i] = (f16)0.f;
    if (hi == 0) {
        r[0] = (f16)w0; r[1] = (f16)w1;
        const float bh = (float)(f16)b;
        r[6] = (f16)bh; r[7] = (f16)(256.f * (b - bh));
    }
    return r;
}

// One GRU cell, 32 j-rows x 32 batch via 32x32x16 MFMA. Biases + (optional)
// rank-2 x-path enter via the extras MFMA (C starts at 0). Epilogue math
// bit-identical to the 8x-passing kernels.
template<bool XM>
__device__ __forceinline__ void cell32(
    const f16x8 (&Wh)[3][4], const f16x8 (&Wx)[3][4], const f16x8 (&ex)[4], f16x8 exB,
    const f16* __restrict__ Xs, const f16* __restrict__ Hs, f16* __restrict__ Dst,
    f16x4 (&ho)[4], const int (&rd)[4], const int (&wr)[4])
{
    f32x16 z;
    #pragma unroll
    for (int i = 0; i < 16; ++i) z[i] = 0.f;
    f32x16 aR  = mfma32(ex[0], exB, z);
    f32x16 aZ  = mfma32(ex[1], exB, z);
    f32x16 aNi = mfma32(ex[2], exB, z);
    f32x16 aNh = mfma32(ex[3], exB, z);
    #pragma unroll
    for (int f = 0; f < 4; ++f) {
        const f16x8 hb = *(const f16x8*)(Hs + rd[f]);
        aR  = mfma32(Wh[0][f], hb, aR);
        aZ  = mfma32(Wh[1][f], hb, aZ);
        aNh = mfma32(Wh[2][f], hb, aNh);
        if constexpr (XM) {
            const f16x8 xb = *(const f16x8*)(Xs + rd[f]);
            aR  = mfma32(Wx[0][f], xb, aR);
            aZ  = mfma32(Wx[1][f], xb, aZ);
            aNi = mfma32(Wx[2][f], xb, aNi);
        }
    }
    f16x4 o[4];
    #pragma unroll
    for (int r = 0; r < 16; ++r) {
        const float rr = __builtin_amdgcn_rcpf(1.f + exp2r(aR[r]));
        const float zz = __builtin_amdgcn_rcpf(1.f + exp2r(aZ[r]));
        const float n  = 1.f - 2.f * __builtin_amdgcn_rcpf(1.f + exp2r(aNi[r] + rr * aNh[r]));
        const float h  = n + zz * ((float)ho[r >> 2][r & 3] - n);
        o[r >> 2][r & 3] = (f16)h;
    }
    #pragma unroll
    for (int g = 0; g < 4; ++g) { ho[g] = o[g]; *(f16x4*)(Dst + wr[g]) = o[g]; }
}

// 256 thr = 4 waves: 2 L0-role (j-halves) + 2 L1-role, role-rotated by block
// parity so each SIMD hosts one L0 + one L1 wave from different blocks.
// Batch tile 64, halves A/B with the R8-verified layer-split skew schedule.
// h layout: [batch][j] f16, 16B groups XOR-swizzled: phys = b*64 +
// (((j>>3) ^ (b&7))<<3) + (j&7)  -> conflict-free b128 reads (derivation in
// journal); writes are 4x b64 per lane at the D-layout j-groups.
__global__ __launch_bounds__(256, 2)
void gru_traj_w32(
    const float* __restrict__ x,
    const float* __restrict__ eWih0, const float* __restrict__ eWhh0,
    const float* __restrict__ ebih0, const float* __restrict__ ebhh0,
    const float* __restrict__ eWih1, const float* __restrict__ eWhh1,
    const float* __restrict__ ebih1, const float* __restrict__ ebhh1,
    const float* __restrict__ dWih0, const float* __restrict__ dWhh0,
    const float* __restrict__ dbih0, const float* __restrict__ dbhh0,
    const float* __restrict__ dWih1, const float* __restrict__ dWhh1,
    const float* __restrict__ dbih1, const float* __restrict__ dbhh1,
    const float* __restrict__ fcW,  const float* __restrict__ fcb,
    float* __restrict__ out)
{
    __shared__ f16 h0s[2 * 2 * 2048];   // [par][half][32b x 64j], 16 KB
    __shared__ f16 h1s[2 * 2 * 2048];   // 16 KB
    __shared__ float2 xs[T_SEQ * 64];   // [t][row], 5.5 KB
#define H0(p, hf) (h0s + ((p) * 2 + (hf)) * 2048)
#define H1(p, hf) (h1s + ((p) * 2 + (hf)) * 2048)

    const int tid  = threadIdx.x;
    const int lane = tid & 63;
    const int wv   = __builtin_amdgcn_readfirstlane(tid >> 6);
    const int wvr  = (wv + ((blockIdx.x & 1) << 1)) & 3;   // role rotation
    const bool isL0 = wvr < 2;
    const int jh   = wvr & 1;           // j-half: rows jh*32 .. +31
    const int b31  = lane & 31;
    const int hi   = lane >> 5;
    const int b7   = b31 & 7;
    const int r0   = blockIdx.x * 64;

    // ---------------- prologue staging ----------------
    {
        const float2* x2 = (const float2*)x;
        for (int i = tid; i < 64 * T_SEQ; i += 256) {
            const int row = i / T_SEQ, t = i - row * T_SEQ;
            xs[t * 64 + row] = x2[(size_t)r0 * T_SEQ + i];
        }
    }
    for (int i = tid; i < 4096; i += 256) { h0s[i] = (f16)0.f; h1s[i] = (f16)0.f; }  // parity 0

    // LDS offsets (f16 units)
    int rd[4], wr[4];
    #pragma unroll
    for (int f = 0; f < 4; ++f) rd[f] = b31 * 64 + (((f * 2 + hi) ^ b7) << 3);
    #pragma unroll
    for (int g = 0; g < 4; ++g) wr[g] = b31 * 64 + ((((jh << 2) + g) ^ b7) << 3) + (hi << 2);

    const int jA = jh * 32 + b31;   // this lane's A-row (j index)

    // constant extras-B (bias channel only): [0..0, 1, 1/256] on lo-lanes
    f16x8 exB1;
    #pragma unroll
    for (int i = 0; i < 8; ++i) exB1[i] = (f16)0.f;
    if (hi == 0) { exB1[6] = (f16)1.f; exB1[7] = (f16)(1.f / 256.f); }
    auto exBx = [&](float2 xv) {   // enc-L0 / peel extras-B: x0,x1 + bias channel
        f16x8 r;
        #pragma unroll
        for (int i = 0; i < 8; ++i) r[i] = (f16)0.f;
        if (hi == 0) { r[0] = (f16)xv.x; r[1] = (f16)xv.y; r[6] = (f16)1.f; r[7] = (f16)(1.f / 256.f); }
        return r;
    };

    f16x4 hoA[4], hoB[4];
    #pragma unroll
    for (int g = 0; g < 4; ++g) {
        #pragma unroll
        for (int i = 0; i < 4; ++i) { hoA[g][i] = (f16)0.f; hoB[g][i] = (f16)0.f; }
    }

    // ---------------- encoder weights ----------------
    f16x8 Wh[3][4], Wx[3][4], ex[4];
    if (isL0) {
        #pragma unroll
        for (int g = 0; g < 3; ++g)
            #pragma unroll
            for (int f = 0; f < 4; ++f)
                Wh[g][f] = afrag32(eWhh0, g * 64 + jh * 32, b31, hi, f, g == 2 ? SNC : SRC);
        ex[0] = ex_make(SRC * eWih0[jA * 2],         SRC * eWih0[jA * 2 + 1],         SRC * (ebih0[jA] + ebhh0[jA]), hi);
        ex[1] = ex_make(SRC * eWih0[(64 + jA) * 2],  SRC * eWih0[(64 + jA) * 2 + 1],  SRC * (ebih0[64 + jA] + ebhh0[64 + jA]), hi);
        ex[2] = ex_make(SNC * eWih0[(128 + jA) * 2], SNC * eWih0[(128 + jA) * 2 + 1], SNC * ebih0[128 + jA], hi);
        ex[3] = ex_make(0.f, 0.f, SNC * ebhh0[128 + jA], hi);
    } else {
        #pragma unroll
        for (int g = 0; g < 3; ++g)
            #pragma unroll
            for (int f = 0; f < 4; ++f) {
                const float sc = g == 2 ? SNC : SRC;
                Wh[g][f] = afrag32(eWhh1, g * 64 + jh * 32, b31, hi, f, sc);
                Wx[g][f] = afrag32(eWih1, g * 64 + jh * 32, b31, hi, f, sc);
            }
        ex[0] = ex_make(0.f, 0.f, SRC * (ebih1[jA] + ebhh1[jA]), hi);
        ex[1] = ex_make(0.f, 0.f, SRC * (ebih1[64 + jA] + ebhh1[64 + jA]), hi);
        ex[2] = ex_make(0.f, 0.f, SNC * ebih1[128 + jA], hi);
        ex[3] = ex_make(0.f, 0.f, SNC * ebhh1[128 + jA], hi);
    }
    __syncthreads();

    // ---------------- encoder (R8-verified skew) ----------------
    #pragma unroll 1
    for (int t = 0; t < T_SEQ; ++t) {
        const int pr = t & 1, pw = pr ^ 1;
        if (isL0) {        // L0enc(t,A)
            cell32<false>(Wh, Wh, ex, exBx(xs[t * 64 + b31]),
                          nullptr, H0(pr, 0), H0(pw, 0), hoA, rd, wr);
        } else if (t > 0) { // L1enc(t-1,B)
            cell32<true>(Wh, Wx, ex, exB1, H0(pr, 1), H1(pw, 1), H1(pr, 1), hoB, rd, wr);
        }
        __syncthreads();
        if (isL0) {        // L0enc(t,B)
            cell32<false>(Wh, Wh, ex, exBx(xs[t * 64 + 32 + b31]),
                          nullptr, H0(pr, 1), H0(pw, 1), hoB, rd, wr);
        } else {           // L1enc(t,A)
            cell32<true>(Wh, Wx, ex, exB1, H0(pw, 0), H1(pr, 0), H1(pw, 0), hoA, rd, wr);
        }
        __syncthreads();
    }
    if (!isL0)   // drain L1enc(10,B)
        cell32<true>(Wh, Wx, ex, exB1, H0(1, 1), H1(0, 1), H1(1, 1), hoB, rd, wr);
    __syncthreads();
    // h0 parity 1, h1 parity 1 (both halves)

    // ---------------- phase switch ----------------
    f16x8 fcA[4];
    float fcb0 = fcb[0], fcb1 = fcb[1];
    if (isL0) {
        #pragma unroll
        for (int g = 0; g < 3; ++g)
            #pragma unroll
            for (int f = 0; f < 4; ++f)
                Wh[g][f] = afrag32(dWhh0, g * 64 + jh * 32, b31, hi, f, g == 2 ? SNC : SRC);
        // peel extras: raw dWih0 x-weights + plain dec biases (no fc fold)
        ex[0] = ex_make(SRC * dWih0[jA * 2],         SRC * dWih0[jA * 2 + 1],         SRC * (dbih0[jA] + dbhh0[jA]), hi);
        ex[1] = ex_make(SRC * dWih0[(64 + jA) * 2],  SRC * dWih0[(64 + jA) * 2 + 1],  SRC * (dbih0[64 + jA] + dbhh0[64 + jA]), hi);
        ex[2] = ex_make(SNC * dWih0[(128 + jA) * 2], SNC * dWih0[(128 + jA) * 2 + 1], SNC * dbih0[128 + jA], hi);
        ex[3] = ex_make(0.f, 0.f, SNC * dbhh0[128 + jA], hi);
    } else {
        #pragma unroll
        for (int g = 0; g < 3; ++g)
            #pragma unroll
            for (int f = 0; f < 4; ++f) {
                const float sc = g == 2 ? SNC : SRC;
                Wh[g][f] = afrag32(dWhh1, g * 64 + jh * 32, b31, hi, f, sc);
                Wx[g][f] = afrag32(dWih1, g * 64 + jh * 32, b31, hi, f, sc);
            }
        ex[0] = ex_make(0.f, 0.f, SRC * (dbih1[jA] + dbhh1[jA]), hi);
        ex[1] = ex_make(0.f, 0.f, SRC * (dbih1[64 + jA] + dbhh1[64 + jA]), hi);
        ex[2] = ex_make(0.f, 0.f, SNC * dbih1[128 + jA], hi);
        ex[3] = ex_make(0.f, 0.f, SNC * dbhh1[128 + jA], hi);
        #pragma unroll
        for (int f = 0; f < 4; ++f) {
            f16x8 r;
            #pragma unroll
            for (int i = 0; i < 8; ++i) r[i] = (f16)0.f;
            if (b31 < 2) {
                const int k0 = f * 16 + hi * 8;
                #pragma unroll
                for (int i = 0; i < 8; ++i) r[i] = (f16)fcW[b31 * 64 + k0 + i];
            }
            fcA[f] = r;
        }
    }

    // FC: L1 wave jh owns half jh. D rows 0,1 live on lo-lanes regs 0,1.
    float* op = out + (size_t)(r0 + jh * 32 + b31) * (STEPS * 2);
    auto FCOUT = [&](const f16* __restrict__ h1c) {
        f32x16 pc;
        #pragma unroll
        for (int i = 0; i < 16; ++i) pc[i] = 0.f;
        if (hi == 0) { pc[0] = fcb0; pc[1] = fcb1; }
        #pragma unroll
        for (int f = 0; f < 4; ++f) {
            const f16x8 hb = *(const f16x8*)(h1c + rd[f]);
            pc = mfma32(fcA[f], hb, pc);
        }
        if (hi == 0) *(float2*)op = make_float2(pc[0], pc[1]);
        op += 2;
    };

    // ---------------- decoder s=0 peel (x-path via extras) ----------------
    if (isL0)   // L0dec(0,A)
        cell32<false>(Wh, Wh, ex, exBx(xs[10 * 64 + b31]),
                      nullptr, H0(1, 0), H0(0, 0), hoA, rd, wr);
    __syncthreads();
    if (isL0) { // L0dec(0,B)
        cell32<false>(Wh, Wh, ex, exBx(xs[10 * 64 + 32 + b31]),
                      nullptr, H0(1, 1), H0(0, 1), hoB, rd, wr);
    } else {    // L1dec(0,A)
        cell32<true>(Wh, Wx, ex, exB1, H0(0, 0), H1(1, 0), H1(0, 0), hoA, rd, wr);
    }
    __syncthreads();

    // L0: swap to steady decoder config (composed x over h1, fc-folded biases)
    if (isL0) {
        #pragma unroll
        for (int g = 0; g < 3; ++g)
            #pragma unroll
            for (int f = 0; f < 4; ++f)
                Wx[g][f] = cfrag32(dWih0, fcW, g * 64 + jh * 32, b31, hi, f, g == 2 ? SNC : SRC);
        ex[0] = ex_make(0.f, 0.f, SRC * (dbih0[jA] + dbhh0[jA] + dWih0[jA * 2] * fcb0 + dWih0[jA * 2 + 1] * fcb1), hi);
        ex[1] = ex_make(0.f, 0.f, SRC * (dbih0[64 + jA] + dbhh0[64 + jA] + dWih0[(64 + jA) * 2] * fcb0 + dWih0[(64 + jA) * 2 + 1] * fcb1), hi);
        ex[2] = ex_make(0.f, 0.f, SNC * (dbih0[128 + jA] + dWih0[(128 + jA) * 2] * fcb0 + dWih0[(128 + jA) * 2 + 1] * fcb1), hi);
        ex[3] = ex_make(0.f, 0.f, SNC * dbhh0[128 + jA], hi);
    }

    // ---------------- decoder s=1..79 ----------------
    #pragma unroll 1
    for (int s = 1; s < STEPS; ++s) {
        const int pr = s & 1, pw = pr ^ 1;
        if (isL0) {   // L0dec(s,A): x = h1(s-1,A)
            cell32<true>(Wh, Wx, ex, exB1, H1(pw, 0), H0(pw, 0), H0(pr, 0), hoA, rd, wr);
        } else {      // L1dec(s-1,B) + FC(s-1,A) on jh0
            cell32<true>(Wh, Wx, ex, exB1, H0(pw, 1), H1(pr, 1), H1(pw, 1), hoB, rd, wr);
            if (jh == 0) FCOUT(H1(pw, 0));
        }
        __syncthreads();
        if (isL0) {   // L0dec(s,B)
            cell32<true>(Wh, Wx, ex, exB1, H1(pw, 1), H0(pw, 1), H0(pr, 1), hoB, rd, wr);
        } else {      // L1dec(s,A) + FC(s-1,B) on jh1
            cell32<true>(Wh, Wx, ex, exB1, H0(pr, 0), H1(pw, 0), H1(pr, 0), hoA, rd, wr);
            if (jh == 1) FCOUT(H1(pw, 1));
        }
        __syncthreads();
    }
    // drain: L1dec(79,B) + FC(79,A); then FC(79,B)
    if (!isL0) {
        cell32<true>(Wh, Wx, ex, exB1, H0(1, 1), H1(0, 1), H1(1, 1), hoB, rd, wr);
        if (jh == 0) FCOUT(H1(1, 0));
    }
    __syncthreads();
    if (!isL0 && jh == 1) FCOUT(H1(1, 1));
#undef H0
#undef H1
}

extern "C" void kernel_launch(void* const* d_in, const int* in_sizes, int n_in,
                              void* d_out, int out_size, void* d_ws, size_t ws_size,
                              hipStream_t stream) {
    (void)n_in; (void)out_size; (void)d_ws; (void)ws_size;

    const float* x     = (const float*)d_in[0];
    const float* eWih0 = (const float*)d_in[1];
    const float* eWhh0 = (const float*)d_in[2];
    const float* ebih0 = (const float*)d_in[3];
    const float* ebhh0 = (const float*)d_in[4];
    const float* eWih1 = (const float*)d_in[5];
    const float* eWhh1 = (const float*)d_in[6];
    const float* ebih1 = (const float*)d_in[7];
    const float* ebhh1 = (const float*)d_in[8];
    const float* dWih0 = (const float*)d_in[9];
    const float* dWhh0 = (const float*)d_in[10];
    const float* dbih0 = (const float*)d_in[11];
    const float* dbhh0 = (const float*)d_in[12];
    const float* dWih1 = (const float*)d_in[13];
    const float* dWhh1 = (const float*)d_in[14];
    const float* dbih1 = (const float*)d_in[15];
    const float* dbhh1 = (const float*)d_in[16];
    const float* fcW   = (const float*)d_in[17];
    const float* fcb   = (const float*)d_in[18];
    float* out = (float*)d_out;

    const int b = in_sizes[0] / (T_SEQ * 2);   // 32768
    dim3 grid(b / 64), block(256);
    hipLaunchKernelGGL(gru_traj_w32, grid, block, 0, stream,
        x, eWih0, eWhh0, ebih0, ebhh0, eWih1, eWhh1, ebih1, ebhh1,
        dWih0, dWhh0, dbih0, dbhh0, dWih1, dWhh1, dbih1, dbhh1,
        fcW, fcb, out);
}